// Round 1
// 300.937 us; speedup vs baseline: 1.0045x; 1.0045x over previous
//
#include <hip/hip_runtime.h>

static constexpr int VD = 16;     // vertex feature dim
static constexpr int SD = 64;     // state dim
static constexpr int ED = 16;     // edge feature dim
static constexpr int RH = 10, RD = 32;
static constexpr int N_ITERS = 3;

typedef __attribute__((ext_vector_type(8))) short short8;
typedef __attribute__((ext_vector_type(4))) float floatx4;

__device__ __forceinline__ float sigmoid_f(float x) {
    return 1.f / (1.f + __expf(-x));
}
__device__ __forceinline__ float tanh_f(float x) {
    x = fminf(fmaxf(x, -20.f), 20.f);
    float e = __expf(2.f * x);
    return (e - 1.f) / (e + 1.f);
}
__device__ __forceinline__ unsigned short f2bf(float x) {   // round-to-nearest-even
    unsigned u = __float_as_uint(x);
    unsigned r = (u + 0x7FFFu + ((u >> 16) & 1u)) >> 16;
    return (unsigned short)r;
}
__device__ __forceinline__ float bf2f(unsigned short s) {
    return __uint_as_float(((unsigned)s) << 16);
}

// One-time bf16 weight transposes for MFMA B-operands ([n][k] layout).
__global__ void prep_w_kernel(const float* __restrict__ W_msg,
                              const float* __restrict__ W_i, const float* __restrict__ W_h,
                              const float* __restrict__ W_embed,
                              unsigned short* __restrict__ WabT, unsigned short* __restrict__ WiT,
                              unsigned short* __restrict__ WhT, unsigned short* __restrict__ W3T,
                              unsigned short* __restrict__ WeT) {
    int i = blockIdx.x * blockDim.x + threadIdx.x;
    if (i < 128*64) {                       // WabT[n][k]: n<64 -> W1 col n; else W2 col n-64
        int n = i >> 6, k = i & 63;
        WabT[i] = f2bf(W_msg[((n < 64 ? 0 : 64) + k)*64 + (n & 63)]);
    }
    int j = i - 128*64;
    if (j >= 0 && j < 192*64) {             // WiT/WhT[n][k] = W[k][n]
        int n = j >> 6, k = j & 63;
        WiT[j] = f2bf(W_i[k*192 + n]);
        WhT[j] = f2bf(W_h[k*192 + n]);
    }
    int l = i - 128*64 - 192*64;
    if (l >= 0 && l < 64*32) {              // W3T[n][k], k padded 16->32 with zeros
        int n = l >> 5, k = l & 31;
        W3T[l] = (k < 16) ? f2bf(W_msg[(128+k)*64 + n]) : (unsigned short)0;
    }
    int m = i - 128*64 - 192*64 - 64*32;
    if (m >= 0 && m < 64*32) {              // WeT[n][k], k padded 16->32 (embed)
        int n = m >> 5, k = m & 31;
        WeT[m] = (k < 16) ? f2bf(W_embed[k*64 + n]) : (unsigned short)0;
    }
}

__global__ void hist_kernel(const int* __restrict__ edge_dst, int* __restrict__ deg, int n_edges) {
    for (int e = blockIdx.x*blockDim.x + threadIdx.x; e < n_edges; e += gridDim.x*blockDim.x)
        atomicAdd(&deg[edge_dst[e]], 1);
}

// Exclusive scan of EVEN-PADDED degrees -> row_ptr. Shuffle-based: 2 barriers total.
__global__ __launch_bounds__(1024) void scan_kernel(const int* __restrict__ deg,
                                                    int* __restrict__ row_ptr,
                                                    int n_nodes) {
    __shared__ int wsum[16];
    int lid = threadIdx.x, lane = lid & 63, wv = lid >> 6;
    int C = (n_nodes + 1023) >> 10;
    int start = lid * C;
    int lsum = 0;
    for (int i = 0; i < C; ++i) {
        int idx = start + i;
        if (idx < n_nodes) lsum += (deg[idx] + 1) & ~1;
    }
    int x = lsum;                              // wave inclusive scan
    #pragma unroll
    for (int off = 1; off < 64; off <<= 1) {
        int y = __shfl_up(x, off);
        if (lane >= off) x += y;
    }
    if (lane == 63) wsum[wv] = x;
    __syncthreads();
    if (wv == 0 && lane < 16) {
        int t = wsum[lane];
        #pragma unroll
        for (int off = 1; off < 16; off <<= 1) {
            int y = __shfl_up(t, off);
            if (lane >= off) t += y;
        }
        wsum[lane] = t;
    }
    __syncthreads();
    int wbase = (wv > 0) ? wsum[wv - 1] : 0;
    int run = wbase + x - lsum;                // exclusive prefix for this thread
    for (int i = 0; i < C; ++i) {
        int idx = start + i;
        if (idx < n_nodes) { row_ptr[idx] = run; run += (deg[idx] + 1) & ~1; }
    }
}

__global__ void fill_kernel(const int* __restrict__ edge_dst, const int* __restrict__ row_ptr,
                            int* __restrict__ fillc, int* __restrict__ eid, int n_edges) {
    for (int e = blockIdx.x*blockDim.x + threadIdx.x; e < n_edges; e += gridDim.x*blockDim.x) {
        int d = edge_dst[e];
        int ofs = atomicAdd(&fillc[d], 1);
        eid[row_ptr[d] + ofs] = e;
    }
}

// Once: Cp[pair][col] (uint: lo=even edge, hi=odd edge) = edge_data@W3 (bf16) + src_csr gather.
// One wave per 16-position tile. Pair partner e^1 is in the SAME lane (regs r, r+1) ->
// pack one dense 4-byte store per pair (perfect coalescing, half the store count).
__global__ __launch_bounds__(256) void edgeconst_kernel(
        const int* __restrict__ eid, const int* __restrict__ edge_src,
        const float* __restrict__ edge_data, const unsigned short* __restrict__ W3T,
        int* __restrict__ src_csr, unsigned short* __restrict__ Cp, int Lmax) {
    int w = blockIdx.x * 4 + (threadIdx.x >> 6);
    int lane = threadIdx.x & 63;
    int e0 = w * 16;
    if (e0 >= Lmax) return;
    int quad = lane >> 4, l16 = lane & 15;
    int erow = e0 + l16;
    int ev = eid[erow];                      // coalesced; 0 for pads
    if (quad == 0) src_csr[erow] = edge_src[ev];
    short8 a0 = {0,0,0,0,0,0,0,0};           // k = quad*8..+8; real only k<16
    if (quad < 2) {
        const float4* ep = (const float4*)(edge_data + (size_t)ev*ED + quad*8);
        float4 x0 = ep[0], x1 = ep[1];
        a0[0]=(short)f2bf(x0.x); a0[1]=(short)f2bf(x0.y); a0[2]=(short)f2bf(x0.z); a0[3]=(short)f2bf(x0.w);
        a0[4]=(short)f2bf(x1.x); a0[5]=(short)f2bf(x1.y); a0[6]=(short)f2bf(x1.z); a0[7]=(short)f2bf(x1.w);
    }
    floatx4 z4 = {0.f,0.f,0.f,0.f};
    #pragma unroll
    for (int nt = 0; nt < 4; ++nt) {
        int n = nt*16 + l16;
        short8 b0 = *(const short8*)(W3T + (size_t)n*32 + quad*8);
        floatx4 d = __builtin_amdgcn_mfma_f32_16x16x32_bf16(a0, b0, z4, 0, 0, 0);
        #pragma unroll
        for (int rp = 0; rp < 2; ++rp) {     // pair (e, e+1), e = e0+quad*4+2rp (even)
            int e = e0 + quad*4 + 2*rp;
            unsigned pack = (unsigned)f2bf(d[2*rp]) | ((unsigned)f2bf(d[2*rp+1]) << 16);
            *(unsigned*)(Cp + (size_t)(e >> 1)*128 + n*2) = pack;
        }
    }
}

// Embed via MFMA (K=16 padded to 32) + fused iter-0 [A|B]. Block = 16-node tile, 4 waves.
__global__ __launch_bounds__(256) void embed_fused_kernel(
        const float* __restrict__ node_data, const unsigned short* __restrict__ WeT,
        const float* __restrict__ b_embed,
        unsigned short* __restrict__ hb,
        const unsigned short* __restrict__ WabT, const float* __restrict__ b_msg,
        unsigned short* __restrict__ Ab, unsigned short* __restrict__ Bb, int n_nodes) {
    __shared__ unsigned short hs[16 * 68];
    int jt = threadIdx.x >> 6, lane = threadIdx.x & 63;
    int m0 = blockIdx.x * 16;
    if (m0 >= n_nodes) return;
    int quad = lane >> 4, l16 = lane & 15;
    int mrow = m0 + l16; if (mrow >= n_nodes) mrow = n_nodes - 1;
    short8 a0 = {0,0,0,0,0,0,0,0};
    if (quad < 2) {
        const float4* np = (const float4*)(node_data + (size_t)mrow*VD + quad*8);
        float4 x0 = np[0], x1 = np[1];
        a0[0]=(short)f2bf(x0.x); a0[1]=(short)f2bf(x0.y); a0[2]=(short)f2bf(x0.z); a0[3]=(short)f2bf(x0.w);
        a0[4]=(short)f2bf(x1.x); a0[5]=(short)f2bf(x1.y); a0[6]=(short)f2bf(x1.z); a0[7]=(short)f2bf(x1.w);
    }
    int j = jt*16 + l16;
    short8 b0 = *(const short8*)(WeT + (size_t)j*32 + quad*8);
    floatx4 z4 = {0.f,0.f,0.f,0.f};
    floatx4 d = __builtin_amdgcn_mfma_f32_16x16x32_bf16(a0, b0, z4, 0, 0, 0);
    float bias = b_embed[j];
    #pragma unroll
    for (int r = 0; r < 4; ++r) {
        int m = m0 + quad*4 + r;
        unsigned short v16 = f2bf(d[r] + bias);
        hs[(quad*4 + r)*68 + j] = v16;
        if (m < n_nodes) hb[(size_t)m*SD + j] = v16;
    }
    __syncthreads();
    short8 aa0 = *(const short8*)(hs + l16*68 + quad*8);
    short8 aa1 = *(const short8*)(hs + l16*68 + 32 + quad*8);
    #pragma unroll
    for (int s = 0; s < 2; ++s) {
        int ncol = (jt + 4*s)*16 + l16;
        const short8* bp = (const short8*)(WabT + (size_t)ncol*SD + quad*8);
        floatx4 dd = __builtin_amdgcn_mfma_f32_16x16x32_bf16(aa0, bp[0], z4, 0, 0, 0);
        dd = __builtin_amdgcn_mfma_f32_16x16x32_bf16(aa1, bp[4], dd, 0, 0, 0);
        float bias2 = (s == 0) ? b_msg[ncol] : 0.f;
        int jc = jt*16 + l16;
        #pragma unroll
        for (int r = 0; r < 4; ++r) {
            int m = m0 + quad*4 + r;
            if (m >= n_nodes) break;
            float v = dd[r] + bias2;
            if (s == 0) Ab[(size_t)m*SD + jc] = f2bf(v);
            else        Bb[(size_t)m*SD + jc] = f2bf(v);
        }
    }
}

// One full MPNN iteration. Block = 16-node tile, 4 waves.
// Phase 1 (agg): all src_csr + Cp loads issued at chunk top, B-row gathers batched 32-deep
//   as raw u16 (conversion deferred to the accumulate loop) -> deep vmcnt pipeline.
//   __launch_bounds__(256,4) caps at 128 VGPR (grid only supplies ~4.9 blocks/CU anyway),
//   giving the scheduler registers to keep the gather batch in flight.
// Phase 2 (GRU): hbr fragments + hold values hoisted ABOVE the phase-1 barrier to overlap.
// Phase 3: !LAST -> next [A|B] from hnew LDS tile; LAST -> fused readout partials.
template<int FIRST, int LAST>
__global__ __launch_bounds__(256, 4) void mpnn_iter_kernel(
        const unsigned short* __restrict__ hbr, unsigned short* __restrict__ hbw,
        const unsigned short* __restrict__ Abr, const unsigned short* __restrict__ Bbr,
        unsigned short* __restrict__ Abw, unsigned short* __restrict__ Bbw,
        const unsigned short* __restrict__ Cp, const int* __restrict__ src_csr,
        const int* __restrict__ row_ptr, const int* __restrict__ deg,
        unsigned short* __restrict__ m_accb,
        const unsigned short* __restrict__ WiT, const unsigned short* __restrict__ WhT,
        const float* __restrict__ b_i, const float* __restrict__ b_h,
        const unsigned short* __restrict__ WabT, const float* __restrict__ b_msg,
        const float* __restrict__ W_r1, const float* __restrict__ b_r1,
        const float* __restrict__ W_r2, float* __restrict__ partials,
        int n_nodes, int Lcap) {
    __shared__ unsigned short hsm[16 * 68];   // m tile (bf16)
    __shared__ unsigned short hsn[16 * 68];   // hnew tile (bf16)
    int w = threadIdx.x >> 6, lane = threadIdx.x & 63;
    int m0 = blockIdx.x * 16;
    if (m0 >= n_nodes) return;

    // ---- Phase 1: aggregation, 4 nodes per wave ----
    int e0[4], dg[4]; float aval[4], base[4];
    #pragma unroll
    for (int u = 0; u < 4; ++u) {
        int n = m0 + w*4 + u;
        bool v = n < n_nodes;
        int nc = v ? n : n_nodes - 1;
        e0[u] = row_ptr[nc];
        dg[u] = v ? deg[nc] : 0;
        aval[u] = bf2f(Abr[(size_t)nc*SD + lane]);
        base[u] = FIRST ? 0.f : bf2f(m_accb[(size_t)nc*SD + lane]);
    }

    // Hoisted phase-2 inputs: overlap their latency with the aggregation loop.
    int quad = lane >> 4, l16 = lane & 15;
    int mrow = m0 + l16; if (mrow >= n_nodes) mrow = n_nodes - 1;
    const short8* hp = (const short8*)(hbr + (size_t)mrow*SD + quad*8);
    short8 ha0 = hp[0], ha1 = hp[4];
    int j0 = w * 16;
    float hold[4];
    #pragma unroll
    for (int r = 0; r < 4; ++r) {
        int m = m0 + quad*4 + r;
        int mc = m < n_nodes ? m : n_nodes - 1;
        hold[r] = bf2f(hbr[(size_t)mc*SD + (j0 + l16)]);
    }

    float acc[4] = {0.f, 0.f, 0.f, 0.f};
    int mx = max(max(dg[0], dg[1]), max(dg[2], dg[3]));
    for (int c = 0; c*16 < mx; ++c) {
        // 1) issue ALL src_csr loads for this chunk
        int sv[4];
        #pragma unroll
        for (int u = 0; u < 4; ++u) {
            int ilast = e0[u] + (dg[u] > 0 ? dg[u] - 1 : 0);
            int i = e0[u] + c*16 + (lane & 15);
            if (i > ilast) i = ilast;
            sv[u] = src_csr[i];
        }
        // 2) issue ALL Cp loads for this chunk (independent of src)
        unsigned cp2[4][8];
        #pragma unroll
        for (int u = 0; u < 4; ++u) {
            int pb = (e0[u] >> 1) + c*8;
            #pragma unroll
            for (int t2 = 0; t2 < 8; ++t2) {
                int pi = pb + t2; if (pi > Lcap) pi = Lcap;
                cp2[u][t2] = *(const unsigned*)(Cp + (size_t)pi*128 + lane*2);
            }
        }
        // 3) gathers in two 32-deep batches; raw u16, convert at use
        #pragma unroll
        for (int up = 0; up < 2; ++up) {
            unsigned short bv[2][16];
            #pragma unroll
            for (int q = 0; q < 2; ++q) {
                int u = up*2 + q;
                #pragma unroll
                for (int t = 0; t < 16; ++t) {
                    int s = __builtin_amdgcn_readlane(sv[u], t);
                    bv[q][t] = Bbr[(size_t)s*SD + lane];
                }
            }
            #pragma unroll
            for (int q = 0; q < 2; ++q) {
                int u = up*2 + q;
                int cnt = dg[u] - c*16;
                #pragma unroll
                for (int t = 0; t < 16; ++t) {
                    if (t < cnt) {
                        float bvf = bf2f(bv[q][t]);
                        float cv = bf2f((unsigned short)((t & 1) ? (cp2[u][t>>1] >> 16)
                                                                 : (cp2[u][t>>1] & 0xFFFF)));
                        acc[u] += fmaxf(aval[u] + bvf + cv, 0.f);
                    }
                }
            }
        }
    }
    #pragma unroll
    for (int u = 0; u < 4; ++u) {
        int n = m0 + w*4 + u;
        unsigned short nv16 = f2bf(base[u] + acc[u]);
        hsm[(w*4 + u)*68 + lane] = nv16;
        if (!LAST && n < n_nodes) m_accb[(size_t)n*SD + lane] = nv16;
    }
    __syncthreads();

    // ---- Phase 2: GRU via MFMA ----
    short8 ma0 = *(const short8*)(hsm + l16*68 + quad*8);
    short8 ma1 = *(const short8*)(hsm + l16*68 + 32 + quad*8);
    floatx4 di[3], dh[3];
    floatx4 z4 = {0.f,0.f,0.f,0.f};
    #pragma unroll
    for (int g = 0; g < 3; ++g) {
        int n = g*64 + j0 + l16;
        const short8* bi = (const short8*)(WiT + (size_t)n*SD + quad*8);
        const short8* bh = (const short8*)(WhT + (size_t)n*SD + quad*8);
        di[g] = __builtin_amdgcn_mfma_f32_16x16x32_bf16(ma0, bi[0], z4,    0, 0, 0);
        di[g] = __builtin_amdgcn_mfma_f32_16x16x32_bf16(ma1, bi[4], di[g], 0, 0, 0);
        dh[g] = __builtin_amdgcn_mfma_f32_16x16x32_bf16(ha0, bh[0], z4,    0, 0, 0);
        dh[g] = __builtin_amdgcn_mfma_f32_16x16x32_bf16(ha1, bh[4], dh[g], 0, 0, 0);
    }
    int j = j0 + l16;
    float bir = b_i[j], biz = b_i[64+j], bin = b_i[128+j];
    float bhr = b_h[j], bhz = b_h[64+j], bhn = b_h[128+j];
    #pragma unroll
    for (int r = 0; r < 4; ++r) {
        int m = m0 + quad*4 + r;
        float rg = sigmoid_f(di[0][r] + bir + dh[0][r] + bhr);
        float zg = sigmoid_f(di[1][r] + biz + dh[1][r] + bhz);
        float ng = tanh_f(di[2][r] + bin + rg * (dh[2][r] + bhn));
        float hnew = (1.f - zg) * ng + zg * hold[r];
        unsigned short hb16 = f2bf(hnew);
        hsn[(quad*4 + r)*68 + j] = hb16;
        if (!LAST && m < n_nodes) hbw[(size_t)m*SD + j] = hb16;
    }

    if (!LAST) {
        // ---- Phase 3a: next iteration's [A|B] ----
        __syncthreads();
        short8 a0 = *(const short8*)(hsn + l16*68 + quad*8);
        short8 a1 = *(const short8*)(hsn + l16*68 + 32 + quad*8);
        #pragma unroll
        for (int s = 0; s < 2; ++s) {
            int ncol = (w + 4*s)*16 + l16;
            const short8* bp = (const short8*)(WabT + (size_t)ncol*SD + quad*8);
            floatx4 d = __builtin_amdgcn_mfma_f32_16x16x32_bf16(a0, bp[0], z4, 0, 0, 0);
            d = __builtin_amdgcn_mfma_f32_16x16x32_bf16(a1, bp[4], d, 0, 0, 0);
            float bias = (s == 0) ? b_msg[ncol] : 0.f;
            int jc = w*16 + l16;
            #pragma unroll
            for (int r = 0; r < 4; ++r) {
                int m = m0 + quad*4 + r;
                if (m >= n_nodes) break;
                float v = d[r] + bias;
                if (s == 0) Abw[(size_t)m*SD + jc] = f2bf(v);
                else        Bbw[(size_t)m*SD + jc] = f2bf(v);
            }
        }
    } else {
        // ---- Phase 3b: fused readout partials (per-block 32 floats, no atomics) ----
        __syncthreads();
        __shared__ float ts[16 * 12];        // hidden, padded stride
        __shared__ float po[512];
        int tid = threadIdx.x;
        if (tid < 16 * RH) {
            int node = tid / RH, i = tid - node * RH;
            float a = b_r1[i];
            #pragma unroll 8
            for (int k = 0; k < SD; ++k)
                a += bf2f(hsn[node*68 + k]) * W_r1[k*RH + i];
            ts[node*12 + i] = fmaxf(a, 0.f);
        }
        __syncthreads();
        #pragma unroll
        for (int s = 0; s < 2; ++s) {
            int task = tid + s*256;          // (node, c)
            int node = task >> 5, c = task & 31;
            float v = 0.f;
            if (m0 + node < n_nodes) {
                #pragma unroll
                for (int i = 0; i < RH; ++i) v += ts[node*12 + i] * W_r2[i*RD + c];
            }
            po[task] = v;
        }
        __syncthreads();
        if (tid < RD) {
            float s2 = 0.f;
            #pragma unroll
            for (int n = 0; n < 16; ++n) s2 += po[n*32 + tid];
            partials[(size_t)blockIdx.x * RD + tid] = s2;
        }
    }
}

// Final: out[c] = sum over blocks of partials + n_nodes * b_r2[c]. One block.
__global__ __launch_bounds__(1024) void final_sum_kernel(
        const float* __restrict__ partials, const float* __restrict__ b_r2,
        float* __restrict__ out, int mtiles, int n_nodes) {
    __shared__ float red[1024];
    int c = threadIdx.x & 31, g = threadIdx.x >> 5;   // 32 groups x 32 cols
    float s = 0.f;
    for (int t = g; t < mtiles; t += 32) s += partials[(size_t)t*RD + c];
    red[threadIdx.x] = s;
    __syncthreads();
    #pragma unroll
    for (int off = 512; off >= 32; off >>= 1) {
        if ((int)threadIdx.x < off) red[threadIdx.x] += red[threadIdx.x + off];
        __syncthreads();
    }
    if (threadIdx.x < RD) out[threadIdx.x] = red[threadIdx.x] + (float)n_nodes * b_r2[threadIdx.x];
}

extern "C" void kernel_launch(void* const* d_in, const int* in_sizes, int n_in,
                              void* d_out, int out_size, void* d_ws, size_t ws_size,
                              hipStream_t stream) {
    const float* node_data = (const float*)d_in[0];
    const float* edge_data = (const float*)d_in[1];
    const int*   edge_src  = (const int*)d_in[2];
    const int*   edge_dst  = (const int*)d_in[3];
    const float* W_embed   = (const float*)d_in[4];
    const float* b_embed   = (const float*)d_in[5];
    const float* W_msg     = (const float*)d_in[6];
    const float* b_msg     = (const float*)d_in[7];
    const float* W_i       = (const float*)d_in[8];
    const float* b_i       = (const float*)d_in[9];
    const float* W_h       = (const float*)d_in[10];
    const float* b_h       = (const float*)d_in[11];
    const float* W_r1      = (const float*)d_in[12];
    const float* b_r1      = (const float*)d_in[13];
    const float* W_r2      = (const float*)d_in[14];
    const float* b_r2      = (const float*)d_in[15];

    int n_nodes = in_sizes[0] / VD;    // 20000
    int n_edges = in_sizes[2];         // 320000
    int Lmax = n_edges + n_nodes + 64; // padded CSR capacity
    int mtiles = (n_nodes + 15) / 16;

    char* ws = (char*)d_ws;
    size_t off = 0;
    auto alloc = [&](size_t bytes) {
        void* p = ws + off;
        off = (off + bytes + 255) & ~(size_t)255;
        return p;
    };
    unsigned short* m_accb = (unsigned short*)alloc((size_t)n_nodes * SD * 2);
    unsigned short* hbA = (unsigned short*)alloc((size_t)n_nodes * SD * 2);
    unsigned short* hbB = (unsigned short*)alloc((size_t)n_nodes * SD * 2);
    unsigned short* Ab0 = (unsigned short*)alloc((size_t)n_nodes * SD * 2);
    unsigned short* Bb0 = (unsigned short*)alloc((size_t)n_nodes * SD * 2);
    unsigned short* Ab1 = (unsigned short*)alloc((size_t)n_nodes * SD * 2);
    unsigned short* Bb1 = (unsigned short*)alloc((size_t)n_nodes * SD * 2);
    unsigned short* Cp  = (unsigned short*)alloc((size_t)(Lmax + 32) * SD * 2);
    int*   src_csr      = (int*)alloc((size_t)(Lmax + 32) * sizeof(int));
    int*   row_ptr      = (int*)alloc((size_t)(n_nodes + 1) * sizeof(int));
    float* partials     = (float*)alloc((size_t)mtiles * RD * sizeof(float));
    // contiguous zero-init region: deg, fillc, eid (one memset)
    char*  zbase        = (char*)alloc(0);
    int*   deg          = (int*)alloc((size_t)n_nodes * sizeof(int));
    int*   fillc        = (int*)alloc((size_t)n_nodes * sizeof(int));
    int*   eid          = (int*)alloc((size_t)(Lmax + 32) * sizeof(int));
    char*  zend         = (char*)alloc(0);
    unsigned short* WabT = (unsigned short*)alloc(128*64*2);
    unsigned short* WiT  = (unsigned short*)alloc(192*64*2);
    unsigned short* WhT  = (unsigned short*)alloc(192*64*2);
    unsigned short* W3T  = (unsigned short*)alloc(64*32*2);
    unsigned short* WeT  = (unsigned short*)alloc(64*32*2);
    (void)ws_size; (void)n_in;

    hipMemsetAsync(zbase, 0, (size_t)(zend - zbase), stream);

    prep_w_kernel<<<(128*64 + 192*64 + 64*32 + 64*32 + 255)/256, 256, 0, stream>>>(
        W_msg, W_i, W_h, W_embed, WabT, WiT, WhT, W3T, WeT);

    hist_kernel<<<(n_edges + 255)/256, 256, 0, stream>>>(edge_dst, deg, n_edges);
    scan_kernel<<<1, 1024, 0, stream>>>(deg, row_ptr, n_nodes);
    fill_kernel<<<(n_edges + 255)/256, 256, 0, stream>>>(edge_dst, row_ptr, fillc, eid, n_edges);

    int ec_waves = (Lmax + 15) / 16;
    edgeconst_kernel<<<(ec_waves + 3)/4, 256, 0, stream>>>(eid, edge_src, edge_data, W3T,
                                                           src_csr, Cp, Lmax);

    embed_fused_kernel<<<mtiles, 256, 0, stream>>>(node_data, WeT, b_embed, hbA,
                                                   WabT, b_msg, Ab0, Bb0, n_nodes);

    int Lcap = (Lmax >> 1) - 1;
    // it0: read Ab0/Bb0, hbA -> hbB, write Ab1/Bb1
    mpnn_iter_kernel<1,0><<<mtiles, 256, 0, stream>>>(hbA, hbB, Ab0, Bb0, Ab1, Bb1,
        Cp, src_csr, row_ptr, deg, m_accb, WiT, WhT, b_i, b_h, WabT, b_msg,
        W_r1, b_r1, W_r2, partials, n_nodes, Lcap);
    // it1: read Ab1/Bb1, hbB -> hbA, write Ab0/Bb0
    mpnn_iter_kernel<0,0><<<mtiles, 256, 0, stream>>>(hbB, hbA, Ab1, Bb1, Ab0, Bb0,
        Cp, src_csr, row_ptr, deg, m_accb, WiT, WhT, b_i, b_h, WabT, b_msg,
        W_r1, b_r1, W_r2, partials, n_nodes, Lcap);
    // it2 (LAST): read Ab0/Bb0, hbA; fused readout partials, no AB / m / hb writes
    mpnn_iter_kernel<0,1><<<mtiles, 256, 0, stream>>>(hbA, hbB, Ab0, Bb0, Ab1, Bb1,
        Cp, src_csr, row_ptr, deg, m_accb, WiT, WhT, b_i, b_h, WabT, b_msg,
        W_r1, b_r1, W_r2, partials, n_nodes, Lcap);

    final_sum_kernel<<<1, 1024, 0, stream>>>(partials, b_r2, (float*)d_out, mtiles, n_nodes);
}